// Round 7
// baseline (164.527 us; speedup 1.0000x reference)
//
#include <hip/hip_runtime.h>
#include <hip/hip_bf16.h>
#include <stdint.h>

typedef __attribute__((ext_vector_type(8))) short short8;
typedef __attribute__((ext_vector_type(4))) float floatx4;
typedef __attribute__((ext_vector_type(4))) unsigned int uintx4;
typedef __attribute__((ext_vector_type(2))) unsigned int uintx2;
typedef unsigned int u32;

#define HH 64
#define WW 64
#define HWSZ 4096
#define BB 8
#define CIN 256
#define COUT 256
#define NTOT 32768  // B*H*W

// async global->LDS DMA, 16 B per lane; LDS dest = wave-uniform base + lane*16
#define GLL16(g, l)                                                            \
    __builtin_amdgcn_global_load_lds(                                          \
        (const __attribute__((address_space(1))) u32*)(const void*)(g),        \
        (__attribute__((address_space(3))) u32*)(void*)(l), 16, 0, 0)

__device__ __forceinline__ unsigned short f2b(float f) {
    union { float f; unsigned int u; } v; v.f = f;
    unsigned int r = v.u + 0x7FFFu + ((v.u >> 16) & 1u);
    return (unsigned short)(r >> 16);
}
__device__ __forceinline__ float b2f(unsigned short h) {
    union { unsigned int u; float f; } v; v.u = ((unsigned int)h) << 16;
    return v.f;
}

// ---- transpose + cast: [B][Cin][HW] f32 -> [B*HW][Cin] bf16 ---- (unchanged)
__global__ __launch_bounds__(256) void transpose_cast(
        const float* __restrict__ y, const float* __restrict__ x,
        unsigned short* __restrict__ yT, unsigned short* __restrict__ xT) {
    __shared__ float lt[64 * 65];
    int zz = blockIdx.z;
    int which = zz & 1;
    int b = zz >> 1;
    const float* src = which ? x : y;
    unsigned short* dst = which ? xT : yT;
    int p0 = blockIdx.x * 64;
    int c0 = blockIdx.y * 64;
    int t = threadIdx.x;

    const float* sp = src + ((size_t)b * CIN + c0) * HWSZ + p0;
    int chL = t >> 4;
    int pxL = (t & 15) * 4;
    #pragma unroll
    for (int pass = 0; pass < 4; ++pass) {
        int ch = chL + pass * 16;
        float4 v = *(const float4*)(sp + (size_t)ch * HWSZ + pxL);
        lt[ch * 65 + pxL + 0] = v.x;
        lt[ch * 65 + pxL + 1] = v.y;
        lt[ch * 65 + pxL + 2] = v.z;
        lt[ch * 65 + pxL + 3] = v.w;
    }
    __syncthreads();

    int c8 = (t & 7) * 8;
    int pxR = t >> 3;
    unsigned short* dp = dst + ((size_t)b * HWSZ + p0) * CIN + c0 + c8;
    #pragma unroll
    for (int pass = 0; pass < 2; ++pass) {
        int px = pxR + pass * 32;
        unsigned int dw[4];
        #pragma unroll
        for (int j = 0; j < 4; ++j) {
            float lo = lt[(c8 + 2 * j) * 65 + px];
            float hi = lt[(c8 + 2 * j + 1) * 65 + px];
            dw[j] = (unsigned int)f2b(lo) | ((unsigned int)f2b(hi) << 16);
        }
        *(uintx4*)(dp + (size_t)px * CIN) = (uintx4){dw[0], dw[1], dw[2], dw[3]};
    }
}

// ---- weight cast ---- (unchanged)
__global__ void wcast(const float* __restrict__ wq, const float* __restrict__ wk,
                      const float* __restrict__ wv,
                      unsigned short* __restrict__ wqb, unsigned short* __restrict__ wkb,
                      unsigned short* __restrict__ wvb) {
    int idx = blockIdx.x * 256 + threadIdx.x;
    wqb[idx] = f2b(wq[idx]);
    wkb[idx] = f2b(wk[idx]);
    wvb[idx] = f2b(wv[idx]);
}

// ---- GEMM v5: global_load_lds staging, TWO k-chunks per barrier pair ---- (unchanged)
__global__ __launch_bounds__(256)
void gemm_qkv(const unsigned short* __restrict__ wqb, const unsigned short* __restrict__ wkb,
              const unsigned short* __restrict__ wvb,
              const unsigned short* __restrict__ yT, const unsigned short* __restrict__ xT,
              unsigned short* __restrict__ Qb, unsigned short* __restrict__ Kb,
              unsigned short* __restrict__ Vb) {
    __shared__ unsigned short lA[2][128 * 32];   // 2 x 8 KB
    __shared__ unsigned short lB[2][128 * 32];   // 2 x 8 KB

    int z = blockIdx.z;
    const unsigned short* Wb = (z == 0) ? wqb : (z == 1) ? wkb : wvb;
    const unsigned short* In = (z == 0) ? yT : xT;
    unsigned short* Out = (z == 0) ? Qb : (z == 1) ? Kb : Vb;

    int n0 = blockIdx.x * 128;
    int m0 = blockIdx.y * 128;
    int t = threadIdx.x;
    int lane = t & 63;
    int wave = t >> 6;
    int quad = lane >> 4;
    int l16 = lane & 15;
    int wm = (wave >> 1) * 64;
    int wn = (wave & 1) * 64;

    int sA0 = t >> 2;
    int cch = (t & 3) * 8;
    int sB0 = t >> 2;
    int sB1 = 64 + (t >> 2);
    int gnB0 = 4 * (sB0 & 31) + (sB0 >> 5);   // B slot permutation: slot = (n&3)*32 + n>>2
    int gnB1 = 4 * (sB1 & 31) + (sB1 >> 5);

    const unsigned short* gA0 = Wb + (size_t)(m0 + sA0) * CIN + cch;
    const unsigned short* gA1 = Wb + (size_t)(m0 + sA0 + 64) * CIN + cch;
    const unsigned short* gB0 = In + (size_t)(n0 + gnB0) * CIN + cch;
    const unsigned short* gB1 = In + (size_t)(n0 + gnB1) * CIN + cch;

    floatx4 acc[4][4];
    #pragma unroll
    for (int mi = 0; mi < 4; ++mi)
        #pragma unroll
        for (int ni = 0; ni < 4; ++ni)
            acc[mi][ni] = (floatx4){0.f, 0.f, 0.f, 0.f};

    #pragma unroll
    for (int it = 0; it < 4; ++it) {
        int k0 = it * 64;
        #pragma unroll
        for (int bsel = 0; bsel < 2; ++bsel) {
            int ko = k0 + bsel * 32;
            unsigned short* dA = lA[bsel] + wave * 512;
            unsigned short* dB = lB[bsel] + wave * 512;
            GLL16(gA0 + ko, dA);
            GLL16(gA1 + ko, dA + 2048);
            GLL16(gB0 + ko, dB);
            GLL16(gB1 + ko, dB + 2048);
        }
        __syncthreads();

        #pragma unroll
        for (int bsel = 0; bsel < 2; ++bsel) {
            short8 af[4], bf[4];
            #pragma unroll
            for (int mi = 0; mi < 4; ++mi)
                af[mi] = *(const short8*)(lA[bsel] + (wm + mi * 16 + l16) * 32 + quad * 8);
            #pragma unroll
            for (int ni = 0; ni < 4; ++ni)
                bf[ni] = *(const short8*)(lB[bsel] + (ni * 32 + (wn >> 2) + l16) * 32 + quad * 8);
            #pragma unroll
            for (int mi = 0; mi < 4; ++mi)
                #pragma unroll
                for (int ni = 0; ni < 4; ++ni)
                    acc[mi][ni] = __builtin_amdgcn_mfma_f32_16x16x32_bf16(af[mi], bf[ni], acc[mi][ni], 0, 0, 0);
        }
        __syncthreads();
    }

    int colb = n0 + wn + 4 * l16;
    #pragma unroll
    for (int mi = 0; mi < 4; ++mi) {
        #pragma unroll
        for (int r = 0; r < 4; ++r) {
            int row = m0 + wm + mi * 16 + quad * 4 + r;
            unsigned int lo = (unsigned int)f2b(acc[mi][0][r]) | ((unsigned int)f2b(acc[mi][1][r]) << 16);
            unsigned int hi = (unsigned int)f2b(acc[mi][2][r]) | ((unsigned int)f2b(acc[mi][3][r]) << 16);
            *(uintx2*)(Out + (size_t)row * NTOT + colb) = (uintx2){lo, hi};
        }
    }
}

// ---- attention v5: LDS-staged K/V image strips, 8 outputs/thread ----
// grid (2 halves, COUT, BB). Block stages 34 rows x 64 px of K and V into LDS
// (row stride 66 shorts = 33 dwords -> 2-way-max banks), then each thread
// computes 8 outputs with the identical select/compute sequence as v4
// -> bitwise-identical output. Global K/V traffic becomes read-exactly-once.
__global__ __launch_bounds__(256)
void attn(const unsigned short* __restrict__ Q,
          const unsigned short* __restrict__ K,
          const unsigned short* __restrict__ V,
          const float* __restrict__ rel_h,
          const float* __restrict__ rel_w,
          float* __restrict__ out) {
    __shared__ unsigned int lKd[34 * 33];   // 34 rows x 66 shorts (33 dwords)
    __shared__ unsigned int lVd[34 * 33];
    unsigned short* lK = (unsigned short*)lKd;
    unsigned short* lV = (unsigned short*)lVd;

    int half = blockIdx.x;
    int c = blockIdx.y;
    int b = blockIdx.z;
    int t = threadIdx.x;

    size_t nb = (size_t)c * NTOT + (size_t)b * HWSZ;
    const unsigned short* Kp = K + nb;
    const unsigned short* Vp = V + nb;

    int rbase = half * 32 - 1;            // global row of LDS row 0

    // stage 34 rows x 64 px (272 chunks of 8 px), rows clamped to [0,63]
    #pragma unroll
    for (int i = 0; i < 2; ++i) {
        int chunk = i * 256 + t;
        if (chunk < 272) {
            int lr = chunk >> 3;          // 0..33
            int px = (chunk & 7) * 8;
            int gr = rbase + lr;
            gr = gr < 0 ? 0 : (gr > 63 ? 63 : gr);
            uintx4 kv = *(const uintx4*)(Kp + gr * 64 + px);
            uintx4 vv = *(const uintx4*)(Vp + gr * 64 + px);
            int di = lr * 33 + (px >> 1);
            lKd[di + 0] = kv.x; lKd[di + 1] = kv.y; lKd[di + 2] = kv.z; lKd[di + 3] = kv.w;
            lVd[di + 0] = vv.x; lVd[di + 1] = vv.y; lVd[di + 2] = vv.z; lVd[di + 3] = vv.w;
        }
    }
    __syncthreads();

    int r = t >> 3;                       // 0..31 (row within half)
    int c0 = (t & 7) * 8;                 // 0..56 (first output col)
    int hrow = half * 32 + r;             // global output row

    short8 qr = *(const short8*)(Q + nb + hrow * 64 + c0);

    bool use_h = (c < 128);
    float rel3[3];
    if (use_h) {
        rel3[0] = rel_h[c * 3 + 0]; rel3[1] = rel_h[c * 3 + 1]; rel3[2] = rel_h[c * 3 + 2];
    } else {
        int cc = c - 128;
        rel3[0] = rel_w[cc * 3 + 0]; rel3[1] = rel_w[cc * 3 + 1]; rel3[2] = rel_w[cc * 3 + 2];
    }
    float rr[9];
    #pragma unroll
    for (int ri = 0; ri < 3; ++ri)
        #pragma unroll
        for (int j = 0; j < 3; ++j)
            rr[ri * 3 + j] = use_h ? rel3[ri] : rel3[j];

    int e0 = (c0 > 0) ? c0 - 1 : 0;
    int e9 = (c0 < 56) ? c0 + 8 : 63;
    bool okL = (c0 > 0);
    bool okR = (c0 < 56);

    float kb[3][10], vb[3][10];
    #pragma unroll
    for (int ri = 0; ri < 3; ++ri) {
        int lr = r + ri;                  // LDS row for window row (always valid 0..33)
        int grow = half * 32 + r + ri - 1;
        bool rok = (unsigned)grow < 64u;
        int di = lr * 33 + (c0 >> 1);
        #pragma unroll
        for (int j = 0; j < 4; ++j) {
            unsigned int ku = lKd[di + j];
            unsigned int vu = lVd[di + j];
            kb[ri][1 + 2 * j] = rok ? b2f((unsigned short)(ku & 0xffff)) : 0.f;
            kb[ri][2 + 2 * j] = rok ? b2f((unsigned short)(ku >> 16)) : 0.f;
            vb[ri][1 + 2 * j] = rok ? b2f((unsigned short)(vu & 0xffff)) : 0.f;
            vb[ri][2 + 2 * j] = rok ? b2f((unsigned short)(vu >> 16)) : 0.f;
        }
        bool ok0 = rok && okL;
        bool ok9 = rok && okR;
        kb[ri][0] = ok0 ? b2f(lK[lr * 66 + e0]) : 0.f;
        vb[ri][0] = ok0 ? b2f(lV[lr * 66 + e0]) : 0.f;
        kb[ri][9] = ok9 ? b2f(lK[lr * 66 + e9]) : 0.f;
        vb[ri][9] = ok9 ? b2f(lV[lr * 66 + e9]) : 0.f;
    }

    float q[8];
    #pragma unroll
    for (int i = 0; i < 8; ++i) q[i] = b2f((unsigned short)qr[i]);

    float ov[8];
    #pragma unroll
    for (int wi = 0; wi < 8; ++wi) {
        float qv = q[wi];
        float lg[9];
        #pragma unroll
        for (int ri = 0; ri < 3; ++ri)
            #pragma unroll
            for (int j = 0; j < 3; ++j)
                lg[ri * 3 + j] = qv * (kb[ri][wi + j] + rr[ri * 3 + j]);
        float m = lg[0];
        #pragma unroll
        for (int t2 = 1; t2 < 9; ++t2) m = fmaxf(m, lg[t2]);
        float s = 0.f, o = 0.f;
        #pragma unroll
        for (int ri = 0; ri < 3; ++ri)
            #pragma unroll
            for (int j = 0; j < 3; ++j) {
                float e = __expf(lg[ri * 3 + j] - m);
                s += e;
                o += e * vb[ri][wi + j];
            }
        ov[wi] = o * __builtin_amdgcn_rcpf(s);
    }

    size_t oi = ((size_t)b * COUT + c) * HWSZ + (size_t)hrow * 64 + c0;
    *(floatx4*)(out + oi)     = (floatx4){ ov[0], ov[1], ov[2], ov[3] };
    *(floatx4*)(out + oi + 4) = (floatx4){ ov[4], ov[5], ov[6], ov[7] };
}

extern "C" void kernel_launch(void* const* d_in, const int* in_sizes, int n_in,
                              void* d_out, int out_size, void* d_ws, size_t ws_size,
                              hipStream_t stream) {
    const float* x = (const float*)d_in[0];
    const float* y = (const float*)d_in[1];
    const float* wq = (const float*)d_in[2];
    const float* wk = (const float*)d_in[3];
    const float* wv = (const float*)d_in[4];
    const float* rel_h = (const float*)d_in[5];
    const float* rel_w = (const float*)d_in[6];
    float* out = (float*)d_out;

    char* ws = (char*)d_ws;
    unsigned short* yT  = (unsigned short*)(ws);
    unsigned short* xT  = (unsigned short*)(ws + 16777216);
    unsigned short* wqb = (unsigned short*)(ws + 33554432);
    unsigned short* wkb = (unsigned short*)(ws + 33554432 + 131072);
    unsigned short* wvb = (unsigned short*)(ws + 33554432 + 262144);
    unsigned short* Qb  = (unsigned short*)(ws + 33947648);
    unsigned short* Kb  = (unsigned short*)(ws + 33947648 + 16777216);
    unsigned short* Vb  = (unsigned short*)(ws + 33947648 + 33554432);

    transpose_cast<<<dim3(64, 4, 16), 256, 0, stream>>>(y, x, yT, xT);
    wcast<<<256, 256, 0, stream>>>(wq, wk, wv, wqb, wkb, wvb);
    gemm_qkv<<<dim3(256, 2, 3), 256, 0, stream>>>(wqb, wkb, wvb, yT, xT, Qb, Kb, Vb);
    attn<<<dim3(2, 256, 8), 256, 0, stream>>>(Qb, Kb, Vb, rel_h, rel_w, out);
}